// Round 3
// baseline (115.643 us; speedup 1.0000x reference)
//
#include <hip/hip_runtime.h>
#include <math.h>

// Hawkes loglik/compensator, B=4 N=2048 K=50 D=4.
// R3: factored-exp inner loop. exp(-w(ti-tj)) = exp(-w(ti-tref))*exp(w(tj-tref)),
// tref = first time of the j-tile -> all exponents bounded (|w*span| <= ~8),
// inner loop has NO transcendentals: 1 ds_read_b128 (E[j]) + 1 ds_read_b32 (c)
// + 4 conflict-free A-plane reads + 4 FMA.
//  pair_kernel: 144 blocks = 4 batches x 36 lower-tri 256x256 tile pairs,
//    1024 threads (4 j-splits x 256 i). softplus(alpha) in LDS as 4 planes
//    [ty*51 + c] (stride 51 -> random-ty gather conflict-free).
//  finalize_kernel: 4 blocks; mhat/colsum inline, partial sums, log+mask,
//    compensator, writes 8 outputs.

#define NT 50
#define ND 4
#define NB 4
#define NN 2048
#define TILE 256
#define NTI (NN / TILE)              // 8
#define NPAIR (NTI * (NTI + 1) / 2)  // 36
#define APLANE (NT * 51)             // 2550 floats per decay plane
#define THREADS 1024

__device__ __forceinline__ float softplus_stable(float x) {
    return fmaxf(x, 0.0f) + log1pf(__expf(-fabsf(x)));
}

// ---------------- pair kernel ----------------
__global__ __launch_bounds__(THREADS) void pair_kernel(
        const float* __restrict__ times,
        const int*   __restrict__ types,
        const float* __restrict__ alpha_p,
        const float* __restrict__ beta_p,
        float* __restrict__ pr) {
    __shared__ float A_lds[ND * APLANE];        // 40800 B
    __shared__ __align__(16) float4 sh_E[TILE]; // exp(+w_d*(t_j - t_ref))
    __shared__ int   sh_tc[TILE];
    __shared__ float sh_part[3][TILE];

    int blk = blockIdx.x;
    int b = blk / NPAIR;
    int p = blk - b * NPAIR;
    int ti = 0;
    while (p >= ti + 1) { p -= ti + 1; ti++; }
    int tj = p;   // tj <= ti

    int tid = threadIdx.x;

    float w0 = softplus_stable(beta_p[0]);
    float w1 = softplus_stable(beta_p[1]);
    float w2 = softplus_stable(beta_p[2]);
    float w3 = softplus_stable(beta_p[3]);

    // stage softplus(alpha): alpha layout [k][c][d] -> plane d, [k*51 + c]
    for (int idx = tid; idx < NT * NT * ND; idx += THREADS) {
        int k   = idx / (NT * ND);
        int rem = idx - k * (NT * ND);
        int c   = rem >> 2;
        int d   = rem & 3;
        A_lds[d * APLANE + k * 51 + c] = softplus_stable(alpha_p[idx]);
    }

    float t_ref = times[b * NN + tj * TILE];    // wave-uniform scalar load
    if (tid < TILE) {
        float tjv = times[b * NN + tj * TILE + tid];
        sh_tc[tid] = types[b * NN + tj * TILE + tid];
        float dtr = tjv - t_ref;                // in [0, tile span], w*dtr small
        sh_E[tid] = make_float4(__expf(w0 * dtr), __expf(w1 * dtr),
                                __expf(w2 * dtr), __expf(w3 * dtr));
    }

    int i_loc  = tid & (TILE - 1);
    int split  = tid >> 8;                      // 0..3
    int ig     = ti * TILE + i_loc;
    float t_i  = times[b * NN + ig];
    int   ty   = types[b * NN + ig];
    __syncthreads();

    const float* Arow = &A_lds[ty * 51];
    int jmax = (ti == tj) ? i_loc : TILE;       // strict lower triangle

    float a0 = 0.f, a1 = 0.f, a2 = 0.f, a3 = 0.f;
    for (int jl = split; jl < jmax; jl += 4) {
        float4 E = sh_E[jl];                    // broadcast b128
        int   c  = sh_tc[jl];                   // broadcast b32
        a0 = fmaf(Arow[c],              E.x, a0);
        a1 = fmaf(Arow[APLANE + c],     E.y, a1);
        a2 = fmaf(Arow[2 * APLANE + c], E.z, a2);
        a3 = fmaf(Arow[3 * APLANE + c], E.w, a3);
    }
    // fold in exp(-w_d*(t_i - t_ref)) once per thread
    float dti = t_i - t_ref;                    // >= 0, w*dti <= ~8
    float partial = w0 * __expf(-w0 * dti) * a0
                  + w1 * __expf(-w1 * dti) * a1
                  + w2 * __expf(-w2 * dti) * a2
                  + w3 * __expf(-w3 * dti) * a3;

    if (split) sh_part[split - 1][i_loc] = partial;
    __syncthreads();
    if (split == 0) {
        float tot = partial + sh_part[0][i_loc] + sh_part[1][i_loc] + sh_part[2][i_loc];
        pr[(b * NTI + tj) * NN + ig] = tot;
    }
}

// ---------------- finalize kernel (NB blocks x 256) ----------------
__global__ __launch_bounds__(256) void finalize_kernel(
        const float* __restrict__ times,
        const int*   __restrict__ types,
        const float* __restrict__ mask,
        const float* __restrict__ t0,
        const float* __restrict__ t1,
        const float* __restrict__ mu_p,
        const float* __restrict__ alpha_p,
        const float* __restrict__ beta_p,
        const float* __restrict__ pr,
        float* __restrict__ out) {
    __shared__ float colsum[NT * ND];
    __shared__ float mh[NT];
    __shared__ float red[8];

    int b = blockIdx.x;
    int tid = threadIdx.x;

    float w0 = softplus_stable(beta_p[0]);
    float w1 = softplus_stable(beta_p[1]);
    float w2 = softplus_stable(beta_p[2]);
    float w3 = softplus_stable(beta_p[3]);

    if (tid < NT * ND) {
        float s = 0.f;
        #pragma unroll 5
        for (int k = 0; k < NT; ++k)
            s += softplus_stable(alpha_p[k * (NT * ND) + tid]);
        colsum[tid] = s;
    } else if (tid >= 200 && tid < 200 + NT) {
        mh[tid - 200] = softplus_stable(mu_p[tid - 200]);
    }
    __syncthreads();

    float T1 = t1[b];
    float ll = 0.f, cp = 0.f;
    for (int k = 0; k < NN / 256; ++k) {
        int i   = k * 256 + tid;
        int gi  = b * NN + i;
        int ty  = types[gi];
        float m = mask[gi];
        float s = 0.f;
        int tmax = i >> 8;
        for (int tjt = 0; tjt <= tmax; ++tjt)
            s += pr[(b * NTI + tjt) * NN + i];
        float rate = mh[ty] + s;
        ll += __logf(rate + 1e-8f) * m;
        float tt = T1 - times[gi];
        const float* cs = &colsum[ty * ND];
        cp += m * (cs[0] * (1.f - __expf(-w0 * tt)) +
                   cs[1] * (1.f - __expf(-w1 * tt)) +
                   cs[2] * (1.f - __expf(-w2 * tt)) +
                   cs[3] * (1.f - __expf(-w3 * tt)));
    }
    #pragma unroll
    for (int off = 32; off > 0; off >>= 1) {
        ll += __shfl_down(ll, off, 64);
        cp += __shfl_down(cp, off, 64);
    }
    if ((tid & 63) == 0) { red[tid >> 6] = ll; red[4 + (tid >> 6)] = cp; }
    __syncthreads();
    if (tid == 0) {
        float llt = red[0] + red[1] + red[2] + red[3];
        float cpt = red[4] + red[5] + red[6] + red[7];
        float sm = 0.f;
        #pragma unroll 10
        for (int k = 0; k < NT; ++k) sm += mh[k];
        out[b]      = llt;
        out[NB + b] = (T1 - t0[b]) * sm + cpt;
    }
}

extern "C" void kernel_launch(void* const* d_in, const int* in_sizes, int n_in,
                              void* d_out, int out_size, void* d_ws, size_t ws_size,
                              hipStream_t stream) {
    const float* times   = (const float*)d_in[0];
    const int*   types   = (const int*)  d_in[1];
    const float* mask    = (const float*)d_in[2];
    const float* t0      = (const float*)d_in[3];
    const float* t1      = (const float*)d_in[4];
    const float* mu_p    = (const float*)d_in[5];
    const float* alpha_p = (const float*)d_in[6];
    const float* beta_p  = (const float*)d_in[7];
    float* out = (float*)d_out;
    float* pr  = (float*)d_ws;   // NB*NTI*NN floats = 256 KB

    pair_kernel<<<NB * NPAIR, THREADS, 0, stream>>>(times, types, alpha_p, beta_p, pr);
    finalize_kernel<<<NB, 256, 0, stream>>>(times, types, mask, t0, t1,
                                            mu_p, alpha_p, beta_p, pr, out);
}